// Round 12
// baseline (66.191 us; speedup 1.0000x reference)
//
#include <hip/hip_runtime.h>

// DecisionTreePolicy — complete binary tree, depth 15 (32767 nodes).
// Internal 0..16382 (children 2i+1/2i+2), leaves 16383..32766 -> exactly 14
// decisions from root; out[b] = leaf_logits[leaf(b)].
//
// History: R1/R2 gathers 84us. R4 LDS-stream 68.5. R5 16-wave redundancy 78.
// R6 vmcnt(0) 80. R7 depth-2 counted-vmcnt 67.2. R8 prod/cons 70.6. R9
// depth-4 68.9. R10 swizzle+paired@1wave/SIMD 70.7. R11 2 waves/SIMD with
// PARTITIONED rows 64.5 (best) -> latency now hidden, LDS pipe co-binding:
// 8 waves x 13 levels x 5 reads = 528 insts/half = 1.28us vs 1.63us HBM.
// R12 = R11 + (a) paired-children layout: sthr2[n]={thr[2n+1],thr[2n+2]} b64
// + sfeat2[n] u8-pair u16 -> 3 LDS insts/level (pipe 0.77us); (b) obs rows
// padded to 260 floats (stride mod 32 = 4 banks) -> the 4 rows/wave hit
// distinct banks at converged levels: conflict-free.

#define N_PAIR    8191      // parents of internal children: nodes 0..8190
#define N_FEAT    256
#define N_ACT     64
#define BATCH     262144
#define BLOCK     512
#define GRID      256
#define ROWS_PB   (BATCH / GRID)      // 1024 rows per block
#define HROWS     32                  // rows per half-tile (32 KB payload)
#define HALVES    (ROWS_PB / HROWS)   // 32
#define DEPTH     14
#define PFN       4                   // f32x4 per thread per half: 32KB/512thr/16B
#define RSTRIDE4  65                  // padded row stride in f32x4 (260 floats)
#define TSLOTS    (HROWS * RSTRIDE4)  // 2080 f32x4 per buffer (33.3 KB)

typedef float f32x4 __attribute__((ext_vector_type(4)));

__global__ __launch_bounds__(BLOCK, 1) void tree_policy_kernel(
    const float* __restrict__ obs,          // [BATCH][N_FEAT]
    const int*   __restrict__ features,     // [N_NODES]
    const float* __restrict__ thresholds,   // [N_NODES]
    const float* __restrict__ leaf_logits,  // [N_NODES][N_ACT]
    float*       __restrict__ out)          // [BATCH][N_ACT]
{
    __shared__ float2         sthr2 [N_PAIR];       // 65528 B
    __shared__ unsigned short sfeat2[N_PAIR];       // 16382 B
    __shared__ __align__(16) f32x4 buf[2][TSLOTS];  // 2 x 33.3 KB; total ~145 KB

    const int tid  = threadIdx.x;
    const int lane = tid & 63;
    const int wave = tid >> 6;                // 0..7
    const long rowBase = (long)blockIdx.x * ROWS_PB;
    const f32x4* gsrc = (const f32x4*)(obs + rowBase * N_FEAT);

    // ---- tree -> LDS, paired-children layout (one-time; ~82 KB, L2/L3) ----
    for (int i = tid; i < N_PAIR; i += BLOCK) {
        sthr2[i]  = make_float2(thresholds[2 * i + 1], thresholds[2 * i + 2]);
        sfeat2[i] = (unsigned short)((features[2 * i + 1] & 255) |
                                     ((features[2 * i + 2] & 255) << 8));
    }
    const float thr_root  = thresholds[0];
    const int   feat_root = features[0];

    // ---- prologue: fill the depth-2 pipe (halves 0 and 1) ----
    f32x4 pfA[PFN], pfB[PFN];
#pragma unroll
    for (int k = 0; k < PFN; ++k)
        pfA[k] = __builtin_nontemporal_load(&gsrc[0 * (HROWS * N_FEAT / 4) + k * BLOCK + tid]);
#pragma unroll
    for (int k = 0; k < PFN; ++k)
        pfB[k] = __builtin_nontemporal_load(&gsrc[1 * (HROWS * N_FEAT / 4) + k * BLOCK + tid]);

    asm volatile("s_waitcnt lgkmcnt(0)" ::: "memory");   // tree ds_writes done
    __builtin_amdgcn_s_barrier();                        // tree visible to all waves

    // Row ownership: wave w covers rows [4w, 4w+4); 16 lanes duplicate a row.
    const int myrow_id = (wave << 2) | (lane >> 4);   // 0..31
    const int chunk    = lane & 15;                   // this lane's f32x4 chunk

    auto half_body = [&](int h, f32x4 (&pf)[PFN]) {
        const int b = h & 1;
        // (1) counted wait: loads(h) retired. Younger per wave (steady state):
        // other group's 4 loads + previous epilogue's 1 gather + 1 store = 6.
        if (h == 0)                 asm volatile("s_waitcnt vmcnt(4)" ::: "memory");
        else if (h == HALVES - 1)   asm volatile("s_waitcnt vmcnt(2)" ::: "memory");
        else                        asm volatile("s_waitcnt vmcnt(6)" ::: "memory");
        __builtin_amdgcn_sched_barrier(0);
        // (2) regs -> LDS, padded rows: slot s -> row s>>6, chunk s&63
#pragma unroll
        for (int k = 0; k < PFN; ++k) {
            const int s = k * BLOCK + tid;
            buf[b][(s >> 6) * RSTRIDE4 + (s & 63)] = pf[k];
        }
        // (3) re-issue this register group for half h+2
        if (h + 2 < HALVES) {
#pragma unroll
            for (int k = 0; k < PFN; ++k)
                pf[k] = __builtin_nontemporal_load(
                    &gsrc[(long)(h + 2) * (HROWS * N_FEAT / 4) + k * BLOCK + tid]);
        }
        asm volatile("s_waitcnt lgkmcnt(0)" ::: "memory");  // my ds_writes committed
        __builtin_amdgcn_s_barrier();                        // buf[b] visible (write(h)
        __builtin_amdgcn_sched_barrier(0);                   //  vs read(h-2) separated)

        // (4) traversal: 3 LDS insts/level — obs b32 (conflict-free via pad)
        //     + thr-pair b64 + feat-pair u16; one dependent round-trip/level.
        const float* myrow = (const float*)&buf[b][0] + myrow_id * (RSTRIDE4 * 4);
        int   node = 0;
        float tcur = thr_root;
        int   fcur = feat_root;
#pragma unroll
        for (int d = 0; d < DEPTH - 1; ++d) {
            const float    x   = myrow[fcur];
            const float2   tch = sthr2[node];
            const unsigned fp  = sfeat2[node];
            const bool L = (x <= tcur);            // reference NaN semantics
            node = 2 * node + (L ? 1 : 2);
            tcur = L ? tch.x : tch.y;
            fcur = (int)(L ? (fp & 255u) : (fp >> 8));
        }
        {   // last decision peeled: children are leaves (no LDS entries)
            const float x = myrow[fcur];
            node = 2 * node + ((x <= tcur) ? 1 : 2);
        }
        // node = this row's leaf id — every duplicate lane holds it directly.

        // (5) epilogue: no shfl. Lane -> (row, chunk); 16-lane groups store
        //     256 B contiguous; 1 gather + 1 store per thread.
        const long orow = rowBase + (long)h * HROWS + myrow_id;
        const f32x4 v = *(const f32x4*)(leaf_logits + (size_t)node * N_ACT + chunk * 4);
        __builtin_nontemporal_store(v, (f32x4*)(out + orow * N_ACT + chunk * 4));
    };

    for (int hh = 0; hh < HALVES; hh += 2) {
        half_body(hh,     pfA);
        half_body(hh + 1, pfB);
    }
}

extern "C" void kernel_launch(void* const* d_in, const int* in_sizes, int n_in,
                              void* d_out, int out_size, void* d_ws, size_t ws_size,
                              hipStream_t stream) {
    const float* obs         = (const float*)d_in[0];
    const int*   features    = (const int*)  d_in[1];
    const float* thresholds  = (const float*)d_in[2];
    // d_in[3]/d_in[4] (children) unused: tree is complete by construction.
    const float* leaf_logits = (const float*)d_in[5];
    float*       out         = (float*)d_out;

    tree_policy_kernel<<<dim3(GRID), dim3(BLOCK), 0, stream>>>(
        obs, features, thresholds, leaf_logits, out);
}

// Round 13
// 62.444 us; speedup vs baseline: 1.0600x; 1.0600x over previous
//
#include <hip/hip_runtime.h>

// DecisionTreePolicy — complete binary tree, depth 15 (32767 nodes).
// Internal 0..16382 (children 2i+1/2i+2), leaves 16383..32766 -> exactly 14
// decisions from root; out[b] = leaf_logits[leaf(b)].
//
// History: R1/R2 gathers 84us. R4 LDS-stream 68.5. R5 16-wave redundancy 78.
// R6 vmcnt(0)/tile 80. R7 depth-2 counted-vmcnt 67.2. R8 prod/cons 70.6.
// R9 depth-4 68.9. R10 swizzle 70.7. R11 2 waves/SIMD partitioned rows 64.5
// (best). R12 paired-tree+pad 66.2 (LDS pipe not binding either).
// R13 insight: wave w traverses ONLY the rows it stages (4w..4w+3) -> no
// cross-wave dependency on the obs buffer -> ALL loop barriers are overhead.
// Fully wave-independent streaming: global_load_lds DMA (1 inst = 1 obs row),
// per-wave counted vmcnt(1) (own DMA only; store keeps flying; epilogue
// gather's compiler wait = vmcnt(4), leaves fresh DMA in flight). One barrier
// in the whole kernel (tree visibility after cooperative staging).

#define N_INTERN  16383
#define N_FEAT    256
#define N_ACT     64
#define BATCH     262144
#define BLOCK     512
#define GRID      256
#define ROWS_PB   (BATCH / GRID)      // 1024 rows per block
#define HROWS     32                  // rows per half-tile (32 KB)
#define HALVES    (ROWS_PB / HROWS)   // 32
#define DEPTH     14

typedef float f32x4 __attribute__((ext_vector_type(4)));
typedef __attribute__((address_space(3))) void        lds_void_t;
typedef const __attribute__((address_space(1))) void  glob_cvoid_t;

__device__ __forceinline__ void gload16(const void* g, void* l) {
    // async global->LDS DMA: per-lane global addr, wave-uniform LDS base,
    // HW writes lds_base + lane*16.
    __builtin_amdgcn_global_load_lds((glob_cvoid_t*)g, (lds_void_t*)l, 16, 0, 0);
}

__global__ __launch_bounds__(BLOCK, 1) void tree_policy_kernel(
    const float* __restrict__ obs,          // [BATCH][N_FEAT]
    const int*   __restrict__ features,     // [N_NODES]
    const float* __restrict__ thresholds,   // [N_NODES]
    const float* __restrict__ leaf_logits,  // [N_NODES][N_ACT]
    float*       __restrict__ out)          // [BATCH][N_ACT]
{
    __shared__ float         sthr [N_INTERN];        // 64 KB
    __shared__ unsigned char sfeat[N_INTERN];        // 16 KB
    __shared__ __align__(16) float buf[2][HROWS * N_FEAT];  // 2 x 32 KB -> 144 KB

    const int tid  = threadIdx.x;
    const int lane = tid & 63;
    const int wave = tid >> 6;                // 0..7; 2 waves/SIMD
    const long rowBase = (long)blockIdx.x * ROWS_PB;

    // ---- tree -> LDS (cooperative, one-time) ----
    for (int i = tid; i < N_INTERN; i += BLOCK) {
        sthr[i]  = thresholds[i];
        sfeat[i] = (unsigned char)features[i];
    }
    const float thr_root  = thresholds[0];
    const int   feat_root = features[0];

    // Row ownership: wave w stages AND traverses rows [4w, 4w+4) of each half.
    const int myrow_id = (wave << 2) | (lane >> 4);   // 0..31
    const int chunk    = lane & 15;                   // this lane's f32x4 chunk

    // Per-wave DMA of its own 4 rows of half h (4 x 1KB; 1 inst = 1 obs row).
    auto dma = [&](int h) {
        const float* g = obs + (rowBase + (long)h * HROWS + (wave << 2)) * N_FEAT + lane * 4;
        char* l = (char*)&buf[h & 1][(wave << 2) * N_FEAT];
#pragma unroll
        for (int k = 0; k < 4; ++k)
            gload16(g + k * N_FEAT, l + k * 1024);
    };

    // Child-prefetch traversal: obs lookup (fcur in register) runs parallel
    // to children's thr/feat reads -> one dependent LDS round-trip per level.
    auto traverse = [&](int h) -> int {
        const float* myrow = &buf[h & 1][myrow_id * N_FEAT];
        int node = 0; float tcur = thr_root; int fcur = feat_root;
#pragma unroll
        for (int d = 0; d < DEPTH - 1; ++d) {
            const float x   = myrow[fcur];
            const int   c   = 2 * node + 1;
            const float tl  = sthr[c];
            const float trr = sthr[c + 1];
            const int   fl  = sfeat[c];
            const int   fr  = sfeat[c + 1];
            const bool  L   = (x <= tcur);          // reference NaN semantics
            node = L ? c : c + 1;
            tcur = L ? tl : trr;
            fcur = L ? fl : fr;
        }
        const float x = myrow[fcur];                 // last level: children are leaves
        return 2 * node + ((x <= tcur) ? 1 : 2);
    };

    // ---- prologue ----
    dma(0);
    asm volatile("s_waitcnt vmcnt(0) lgkmcnt(0)" ::: "memory");
    __builtin_amdgcn_s_barrier();        // the ONLY barrier: tree visible to all

    // half 0 (peeled: no epilogue yet)
    dma(1);
    __builtin_amdgcn_sched_barrier(0);
    int node_prev = traverse(0);

    for (int h = 1; h < HALVES; ++h) {
        // Own-wave wait: DMA(h) landed (issued one full period ago).
        // h>=2: allow 1 outstanding = previous output store (never drained).
        if (h == 1) asm volatile("s_waitcnt vmcnt(0)" ::: "memory");
        else        asm volatile("s_waitcnt vmcnt(1)" ::: "memory");
        __builtin_amdgcn_sched_barrier(0);
        // epilogue(h-1) gather FIRST (older than the DMA below -> its
        // compiler-inserted use-wait is vmcnt(4): fresh DMA keeps flying)
        const f32x4 v = *(const f32x4*)(leaf_logits + (size_t)node_prev * N_ACT + chunk * 4);
        __builtin_amdgcn_sched_barrier(0);
        if (h + 1 < HALVES) {
            dma(h + 1);
            __builtin_amdgcn_sched_barrier(0);
        }
        const long orow = rowBase + (long)(h - 1) * HROWS + myrow_id;
        __builtin_nontemporal_store(v, (f32x4*)(out + orow * N_ACT + chunk * 4));
        __builtin_amdgcn_sched_barrier(0);
        node_prev = traverse(h);
    }

    // final epilogue (half HALVES-1)
    const f32x4 v = *(const f32x4*)(leaf_logits + (size_t)node_prev * N_ACT + chunk * 4);
    const long orow = rowBase + (long)(HALVES - 1) * HROWS + myrow_id;
    __builtin_nontemporal_store(v, (f32x4*)(out + orow * N_ACT + chunk * 4));
}

extern "C" void kernel_launch(void* const* d_in, const int* in_sizes, int n_in,
                              void* d_out, int out_size, void* d_ws, size_t ws_size,
                              hipStream_t stream) {
    const float* obs         = (const float*)d_in[0];
    const int*   features    = (const int*)  d_in[1];
    const float* thresholds  = (const float*)d_in[2];
    // d_in[3]/d_in[4] (children) unused: tree is complete by construction.
    const float* leaf_logits = (const float*)d_in[5];
    float*       out         = (float*)d_out;

    tree_policy_kernel<<<dim3(GRID), dim3(BLOCK), 0, stream>>>(
        obs, features, thresholds, leaf_logits, out);
}